// Round 4
// baseline (435.215 us; speedup 1.0000x reference)
//
#include <hip/hip_runtime.h>
#include <hip/hip_bf16.h>

// PCC loss: y_hat, y fp32 [64, 3, 256, 256] -> scalar fp32 = 1 - mean_s(pcc_s).
// Fused single-kernel 5-moment reduction with last-block-done finisher.
// Traffic: 100.7 MB read, ~41 KB ws, 4 B out. Roofline ~16 us @ 6.3 TB/s.

constexpr int B_SAMPLES = 64;
constexpr int NPS       = 3 * 256 * 256;   // 196608 elements per sample
constexpr int BPS       = 32;              // blocks per sample -> 2048 blocks (8/CU)
constexpr int CHUNK     = NPS / BPS;       // 6144 elements
constexpr int THREADS   = 256;
constexpr int ITER      = CHUNK / 4 / THREADS;  // 6 float4 loads per input per thread
constexpr int NBLOCKS   = B_SAMPLES * BPS;      // 2048

__device__ __forceinline__ float wave_reduce_sum(float v) {
    #pragma unroll
    for (int off = 32; off > 0; off >>= 1)
        v += __shfl_down(v, off, 64);
    return v;
}

// ws layout: [0..3] uint32 ready-counter (memset to 0 each launch);
//            floats at offset 16: partials[NBLOCKS][5].
__global__ __launch_bounds__(THREADS) void pcc_fused_kernel(
        const float* __restrict__ a, const float* __restrict__ b,
        float* __restrict__ ws, float* __restrict__ out) {
    unsigned int* counter = reinterpret_cast<unsigned int*>(ws);
    float* part = ws + 16;

    const int blk = blockIdx.x;
    const int s   = blk / BPS;
    const int c   = blk % BPS;
    const size_t base = (size_t)s * NPS + (size_t)c * CHUNK;
    const float4* a4 = reinterpret_cast<const float4*>(a + base);
    const float4* b4 = reinterpret_cast<const float4*>(b + base);
    const int t = threadIdx.x;

    float sa = 0.f, sb = 0.f, sab = 0.f, saa = 0.f, sbb = 0.f;
    #pragma unroll
    for (int k = 0; k < ITER; ++k) {
        const int i = t + k * THREADS;
        float4 va = a4[i];
        float4 vb = b4[i];
        sa  += va.x + va.y + va.z + va.w;
        sb  += vb.x + vb.y + vb.z + vb.w;
        sab = fmaf(va.x, vb.x, sab); sab = fmaf(va.y, vb.y, sab);
        sab = fmaf(va.z, vb.z, sab); sab = fmaf(va.w, vb.w, sab);
        saa = fmaf(va.x, va.x, saa); saa = fmaf(va.y, va.y, saa);
        saa = fmaf(va.z, va.z, saa); saa = fmaf(va.w, va.w, saa);
        sbb = fmaf(vb.x, vb.x, sbb); sbb = fmaf(vb.y, vb.y, sbb);
        sbb = fmaf(vb.z, vb.z, sbb); sbb = fmaf(vb.w, vb.w, sbb);
    }

    sa  = wave_reduce_sum(sa);
    sb  = wave_reduce_sum(sb);
    sab = wave_reduce_sum(sab);
    saa = wave_reduce_sum(saa);
    sbb = wave_reduce_sum(sbb);

    __shared__ float lds[4][5];
    const int wid  = t >> 6;
    const int lane = t & 63;
    if (lane == 0) {
        lds[wid][0] = sa; lds[wid][1] = sb; lds[wid][2] = sab;
        lds[wid][3] = saa; lds[wid][4] = sbb;
    }
    __syncthreads();
    if (t == 0) {
        float r0 = 0.f, r1 = 0.f, r2 = 0.f, r3 = 0.f, r4 = 0.f;
        #pragma unroll
        for (int w = 0; w < 4; ++w) {
            r0 += lds[w][0]; r1 += lds[w][1]; r2 += lds[w][2];
            r3 += lds[w][3]; r4 += lds[w][4];
        }
        float* p = part + (size_t)blk * 5;
        p[0] = r0; p[1] = r1; p[2] = r2; p[3] = r3; p[4] = r4;
    }

    // last-block-done: fold all partials in the final arriving block
    __shared__ int is_last;
    __threadfence();                       // publish partials (device scope)
    if (t == 0) {
        unsigned int old = atomicAdd(counter, 1u);
        is_last = (old == (unsigned int)(NBLOCKS - 1));
    }
    __syncthreads();
    if (is_last) {
        __threadfence();                   // acquire all partials
        if (t < 64) {
            const int smp = t;             // one lane per sample
            float fa = 0.f, fb = 0.f, fab = 0.f, faa = 0.f, fbb = 0.f;
            #pragma unroll
            for (int cc = 0; cc < BPS; ++cc) {
                const float* p = part + ((size_t)smp * BPS + cc) * 5;
                fa += p[0]; fb += p[1]; fab += p[2]; faa += p[3]; fbb += p[4];
            }
            const float N = (float)NPS;
            const float cov = fab - fa * fb / N;
            const float va  = faa - fa * fa / N;
            const float vb  = fbb - fb * fb / N;
            float pcc = cov / sqrtf(va * vb);
            pcc = wave_reduce_sum(pcc);
            if (smp == 0) out[0] = 1.0f - pcc / (float)B_SAMPLES;
        }
    }
}

extern "C" void kernel_launch(void* const* d_in, const int* in_sizes, int n_in,
                              void* d_out, int out_size, void* d_ws, size_t ws_size,
                              hipStream_t stream) {
    const float* y_hat = (const float*)d_in[0];
    const float* y     = (const float*)d_in[1];
    float* out = (float*)d_out;
    float* ws  = (float*)d_ws;   // needs 16 + 2048*5 floats ~= 41 KB

    hipMemsetAsync(ws, 0, sizeof(unsigned int), stream);   // zero ready-counter
    pcc_fused_kernel<<<NBLOCKS, THREADS, 0, stream>>>(y_hat, y, ws, out);
}

// Round 5
// 114.989 us; speedup vs baseline: 3.7848x; 3.7848x over previous
//
#include <hip/hip_runtime.h>
#include <hip/hip_bf16.h>

// PCC loss: y_hat, y fp32 [64, 3, 256, 256] -> scalar fp32 = 1 - mean_s(pcc_s).
// Two-kernel single-pass 5-moment reduction. No fences, no atomics.
// Traffic: 100.7 MB read. Roofline ~16 us @ 6.3 TB/s (less if L3-warm).

constexpr int B_SAMPLES = 64;
constexpr int NPS       = 3 * 256 * 256;   // 196608 elements per sample
constexpr int BPS       = 32;              // blocks per sample -> 2048 blocks (8/CU)
constexpr int CHUNK     = NPS / BPS;       // 6144 elements
constexpr int THREADS   = 256;
constexpr int ITER      = CHUNK / 4 / THREADS;  // 6 float4 loads per input per thread
constexpr int NBLOCKS   = B_SAMPLES * BPS;      // 2048

__device__ __forceinline__ float wave_reduce_sum(float v) {
    #pragma unroll
    for (int off = 32; off > 0; off >>= 1)
        v += __shfl_down(v, off, 64);
    return v;
}

__global__ __launch_bounds__(THREADS) void pcc_partial_kernel(
        const float* __restrict__ a, const float* __restrict__ b,
        float* __restrict__ ws) {
    const int blk = blockIdx.x;
    const int s   = blk / BPS;
    const int c   = blk % BPS;
    const size_t base = (size_t)s * NPS + (size_t)c * CHUNK;
    const float4* a4 = reinterpret_cast<const float4*>(a + base);
    const float4* b4 = reinterpret_cast<const float4*>(b + base);
    const int t = threadIdx.x;

    float sa = 0.f, sb = 0.f, sab = 0.f, saa = 0.f, sbb = 0.f;
    #pragma unroll
    for (int k = 0; k < ITER; ++k) {
        const int i = t + k * THREADS;
        float4 va = a4[i];
        float4 vb = b4[i];
        sa  += va.x + va.y + va.z + va.w;
        sb  += vb.x + vb.y + vb.z + vb.w;
        sab = fmaf(va.x, vb.x, sab); sab = fmaf(va.y, vb.y, sab);
        sab = fmaf(va.z, vb.z, sab); sab = fmaf(va.w, vb.w, sab);
        saa = fmaf(va.x, va.x, saa); saa = fmaf(va.y, va.y, saa);
        saa = fmaf(va.z, va.z, saa); saa = fmaf(va.w, va.w, saa);
        sbb = fmaf(vb.x, vb.x, sbb); sbb = fmaf(vb.y, vb.y, sbb);
        sbb = fmaf(vb.z, vb.z, sbb); sbb = fmaf(vb.w, vb.w, sbb);
    }

    sa  = wave_reduce_sum(sa);
    sb  = wave_reduce_sum(sb);
    sab = wave_reduce_sum(sab);
    saa = wave_reduce_sum(saa);
    sbb = wave_reduce_sum(sbb);

    __shared__ float lds[4][5];
    const int wid  = t >> 6;
    const int lane = t & 63;
    if (lane == 0) {
        lds[wid][0] = sa; lds[wid][1] = sb; lds[wid][2] = sab;
        lds[wid][3] = saa; lds[wid][4] = sbb;
    }
    __syncthreads();
    if (t == 0) {
        float r0 = 0.f, r1 = 0.f, r2 = 0.f, r3 = 0.f, r4 = 0.f;
        #pragma unroll
        for (int w = 0; w < 4; ++w) {
            r0 += lds[w][0]; r1 += lds[w][1]; r2 += lds[w][2];
            r3 += lds[w][3]; r4 += lds[w][4];
        }
        float* p = ws + (size_t)blk * 5;
        p[0] = r0; p[1] = r1; p[2] = r2; p[3] = r3; p[4] = r4;
    }
}

__global__ __launch_bounds__(64) void pcc_final_kernel(
        const float* __restrict__ ws, float* __restrict__ out) {
    const int s = threadIdx.x;   // one lane per sample, 64 lanes
    float sa = 0.f, sb = 0.f, sab = 0.f, saa = 0.f, sbb = 0.f;
    #pragma unroll
    for (int c = 0; c < BPS; ++c) {
        const float* p = ws + ((size_t)s * BPS + c) * 5;
        sa += p[0]; sb += p[1]; sab += p[2]; saa += p[3]; sbb += p[4];
    }
    const float N = (float)NPS;
    const float cov = sab - sa * sb / N;
    const float va  = saa - sa * sa / N;
    const float vb  = sbb - sb * sb / N;
    float pcc = cov / sqrtf(va * vb);
    pcc = wave_reduce_sum(pcc);
    if (s == 0) out[0] = 1.0f - pcc / (float)B_SAMPLES;
}

extern "C" void kernel_launch(void* const* d_in, const int* in_sizes, int n_in,
                              void* d_out, int out_size, void* d_ws, size_t ws_size,
                              hipStream_t stream) {
    const float* y_hat = (const float*)d_in[0];
    const float* y     = (const float*)d_in[1];
    float* out = (float*)d_out;
    float* ws  = (float*)d_ws;   // needs 2048*5 floats = 40 KB

    pcc_partial_kernel<<<NBLOCKS, THREADS, 0, stream>>>(y_hat, y, ws);
    pcc_final_kernel<<<1, 64, 0, stream>>>(ws, out);
}